// Round 19
// baseline (120.332 us; speedup 1.0000x reference)
//
#include <hip/hip_runtime.h>
#include <hip/hip_fp16.h>
#include <math.h>

// MonotoneFeatureTransform: rational-quadratic spline per feature + batch standardize.
// B=131072, F=256, K=16. f32 in/out.
// FINAL (R19): composition of best-verified pieces:
//   - FTB=64/SLOTB=4 geometry (R15-verified): wave X load = 256B contiguous,
//     wave f16 S-store = one full 128B line (WRITE_SIZE 72-78 -> 66MB measured),
//     LDS [16][64] float4 bin-major = 0 bank conflicts.
//   - alignbit+popcount scan (R18-verified): 2 instr/knot, no vcc/sgpr serialization.
//   - lb(256,6), batch-8 loads, f16 spill; streaming pass2.
// Plateau ledger: pass1 pinned at 78+-3us across 9 variants (occupancy 31-70%,
// ILP 4-8, prefetch/staging, 3 scan encodings, 2 geometries). VALU-issue-bound
// at ~50% efficiency; floor ~40us unreachable at HIP source level.
// BANNED (measured): nested-ternary select trees (R9 VGPR-collapse),
// lb(256,8)/plain-lb (R4/R7/R8 collapse), data-dependent LDS reads feeding the
// table read (R11/R12 latency chains).

#define FEAT 256
#define KBINS 16
#define BATCH 131072
#define BOUNDF 5.0f
#define MIN_Df 1e-3f
#define MIN_BWf 1e-3f
#define MIN_BHf 1e-3f
#define EPSF 1e-8f

#define FTB 64                 // features per tile
#define FT_TILES 4
#define SLOTB 4                // row slots per block (256 thr / 64 feat)
#define RBB 256                // row-blocks
#define ROWS_PB (BATCH / RBB)  // 512 rows per block
#define ITERB (ROWS_PB / SLOTB) // 128 rows per thread

// Table region, float offsets relative to `tab`.
#define R_P0   0                    // [16][256] float4: cw0*binv, binv, h*delta, h*d0
#define R_P1   16384                // [16][256] float4: dsum, delta, ch0, pad
#define R_KN   32768                // [15][256] interior knots (cw[1..15])
#define R_MEAN 36608                // [256]
#define R_ISTD 36864                // [256]
#define R_PS   37120                // [1024][64] partial sums
#define R_PS2  (R_PS + 1024 * 64)   // [1024][64] partial sumsq
#define TAB_FLOATS (R_PS2 + 1024 * 64)
#define S_ELEMS ((size_t)BATCH * FEAT)
#define S_FLOATS (S_ELEMS / 2)

__global__ __launch_bounds__(256) void k_params(const float* __restrict__ uw,
                                                const float* __restrict__ uh,
                                                const float* __restrict__ ud,
                                                float* __restrict__ tab) {
    int f = threadIdx.x;
    float cw[17], ch[17], dv[17];
    {
        float u[KBINS];
#pragma unroll
        for (int j = 0; j < KBINS; j++) u[j] = uw[f * KBINS + j];
        float m = u[0];
#pragma unroll
        for (int j = 1; j < KBINS; j++) m = fmaxf(m, u[j]);
        float ssum = 0.f;
#pragma unroll
        for (int j = 0; j < KBINS; j++) { u[j] = expf(u[j] - m); ssum += u[j]; }
        float inv = 1.0f / ssum;
        float cum = 0.f;
        cw[0] = -BOUNDF;
#pragma unroll
        for (int j = 1; j < KBINS; j++) {
            float wj = MIN_BWf + (1.0f - MIN_BWf * (float)KBINS) * (u[j - 1] * inv);
            cum += wj;
            cw[j] = 2.0f * BOUNDF * cum - BOUNDF;
        }
        cw[KBINS] = BOUNDF;
    }
    {
        float u[KBINS];
#pragma unroll
        for (int j = 0; j < KBINS; j++) u[j] = uh[f * KBINS + j];
        float m = u[0];
#pragma unroll
        for (int j = 1; j < KBINS; j++) m = fmaxf(m, u[j]);
        float ssum = 0.f;
#pragma unroll
        for (int j = 0; j < KBINS; j++) { u[j] = expf(u[j] - m); ssum += u[j]; }
        float inv = 1.0f / ssum;
        float cum = 0.f;
        ch[0] = -BOUNDF;
#pragma unroll
        for (int j = 1; j < KBINS; j++) {
            float wj = MIN_BHf + (1.0f - MIN_BHf * (float)KBINS) * (u[j - 1] * inv);
            cum += wj;
            ch[j] = 2.0f * BOUNDF * cum - BOUNDF;
        }
        ch[KBINS] = BOUNDF;
    }
    {
        dv[0] = 1.0f;
        dv[KBINS] = 1.0f;
#pragma unroll
        for (int j = 1; j < KBINS; j++) {
            float v = ud[f * (KBINS - 1) + (j - 1)];
            float sp = fmaxf(v, 0.0f) + log1pf(expf(-fabsf(v))); // stable softplus
            dv[j] = MIN_Df + sp;
        }
    }
    // interior knots, feature-minor for coalesced reads
#pragma unroll
    for (int j = 0; j < 15; j++) tab[R_KN + j * 256 + f] = cw[j + 1];
    // packed per-bin params, BIN-MAJOR: [bin][feature]
    float4* P0g = (float4*)(tab + R_P0);
    float4* P1g = (float4*)(tab + R_P1);
#pragma unroll
    for (int i = 0; i < KBINS; i++) {
        float w = cw[i + 1] - cw[i];
        float binv = 1.0f / w;
        float hb = ch[i + 1] - ch[i];
        float delta = hb * binv;
        float4 p0, p1;
        p0.x = cw[i] * binv;
        p0.y = binv;
        p0.z = hb * delta;
        p0.w = hb * dv[i];
        p1.x = dv[i] + dv[i + 1] - 2.0f * delta;
        p1.y = delta;
        p1.z = ch[i];
        p1.w = 0.0f;
        P0g[i * 256 + f] = p0;
        P1g[i * 256 + f] = p1;
    }
}

// alignbit+popcount scan + rational-quadratic eval (bin-major LDS [16][64]).
// w = (w<<1)|signbit(kn[j]-xn); idx = popcount(w) counts kn[j] < xn. Differs
// from (xn>=kn[j]) only at exact ties, where continuity gives identical values.
__device__ __forceinline__ float eval_rq(float xv, float a, float nb,
                                         const float4* __restrict__ sP0,
                                         const float4* __restrict__ sP1,
                                         const float kn[15], int l) {
    float xn = fmaf(xv, a, nb);
    unsigned int w = 0u;
#pragma unroll
    for (int j = 0; j < 15; j++) {
        float d = kn[j] - xn;                                     // independent subs
        w = __builtin_amdgcn_alignbit(w, __float_as_uint(d), 31); // w=(w<<1)|sign(d)
    }
    int idx = __builtin_popcount(w);                              // v_bcnt_u32_b32
    int o = (idx << 6) | l;
    float4 p0 = sP0[o];
    float4 p1 = sP1[o];
    float th = fmaf(xn, p0.y, -p0.x);
    float th2 = th * th;
    float t1m = th - th2;
    float numer = fmaf(p0.z, th2, p0.w * t1m);
    float denom = fmaf(p1.x, t1m, p1.y);
    float s = fmaf(numer, __builtin_amdgcn_rcpf(denom), p1.z);
    return (fabsf(xn) < BOUNDF) ? s : xn;
}

template <bool STORE_S>
__global__ __launch_bounds__(256, 6) void k_pass1(const float* __restrict__ X,
                                                  const float* __restrict__ shiftp,
                                                  const float* __restrict__ scalep,
                                                  float* __restrict__ tab,
                                                  unsigned short* __restrict__ S) {
    __shared__ float4 sP0[16 * FTB];
    __shared__ float4 sP1[16 * FTB];
    __shared__ float red[2][SLOTB][FTB];
    int t = threadIdx.x;
    int rb = blockIdx.x, ft = blockIdx.y;
    const float4* P0g = (const float4*)(tab + R_P0);
    const float4* P1g = (const float4*)(tab + R_P1);
    for (int s = t; s < 16 * FTB; s += 256) {
        int bin = s >> 6, li = s & 63;
        sP0[s] = P0g[bin * 256 + ft * FTB + li];
        sP1[s] = P1g[bin * 256 + ft * FTB + li];
    }
    int l = t & 63, slot = t >> 6;
    int f = ft * FTB + l;
    float kn[15];
#pragma unroll
    for (int j = 0; j < 15; j++) kn[j] = tab[R_KN + j * 256 + f];
    float a = 1.0f / scalep[f];
    float nb = -shiftp[f] * a;
    __syncthreads();
    size_t base = ((size_t)rb * ROWS_PB + slot) * FEAT + f;
    const float* Xp = X + base;
    unsigned short* Sp = STORE_S ? (S + base) : nullptr;
    float sum = 0.f, sumsq = 0.f;
    for (int r = 0; r < ITERB; r += 8) {
        float xv[8];
#pragma unroll
        for (int i = 0; i < 8; i++) xv[i] = Xp[i * SLOTB * FEAT];
        Xp += 8 * SLOTB * FEAT;
        float sv[8];
#pragma unroll
        for (int i = 0; i < 8; i++) sv[i] = eval_rq(xv[i], a, nb, sP0, sP1, kn, l);
        if (STORE_S) {
#pragma unroll
            for (int i = 0; i < 8; i++) Sp[i * SLOTB * FEAT] = __half_as_ushort(__float2half(sv[i]));
            Sp += 8 * SLOTB * FEAT;
        }
#pragma unroll
        for (int i = 0; i < 8; i++) { sum += sv[i]; sumsq = fmaf(sv[i], sv[i], sumsq); }
    }
    red[0][slot][l] = sum;
    red[1][slot][l] = sumsq;
    __syncthreads();
    if (t < FTB) {
        float v = 0.f;
#pragma unroll
        for (int s2i = 0; s2i < SLOTB; s2i++) v += red[0][s2i][t];
        tab[R_PS + (ft * RBB + rb) * FTB + t] = v;
    } else if (t < 2 * FTB) {
        int u = t - FTB;
        float v = 0.f;
#pragma unroll
        for (int s2i = 0; s2i < SLOTB; s2i++) v += red[1][s2i][u];
        tab[R_PS2 + (ft * RBB + rb) * FTB + u] = v;
    }
}

__global__ __launch_bounds__(256) void k_reduce(float* __restrict__ tab) {
    int f = blockIdx.x;
    int ft = f >> 6, l = f & 63;
    int t = threadIdx.x;
    __shared__ float r1[256], r2[256];
    r1[t] = tab[R_PS + (ft * RBB + t) * FTB + l];
    r2[t] = tab[R_PS2 + (ft * RBB + t) * FTB + l];
    __syncthreads();
    for (int off = 128; off > 0; off >>= 1) {
        if (t < off) { r1[t] += r1[t + off]; r2[t] += r2[t + off]; }
        __syncthreads();
    }
    if (t == 0) {
        float mean = r1[0] * (1.0f / (float)BATCH);
        float var = r2[0] * (1.0f / (float)BATCH) - mean * mean;
        var = fmaxf(var, 0.0f);
        tab[R_MEAN + f] = mean;
        tab[R_ISTD + f] = 1.0f / sqrtf(var + EPSF);
    }
}

// Streaming standardize: z = s*istd - mean*istd, s from f16 buffer.
__global__ __launch_bounds__(256, 8) void k_pass2_stream(const unsigned short* __restrict__ S,
                                                         const float* __restrict__ tab,
                                                         float* __restrict__ Z) {
    int gid = blockIdx.x * 256 + threadIdx.x;   // 524288 threads
    int fg = gid & 31;                          // feature-group: features fg*8 .. fg*8+7
    int rs = gid >> 5;                          // row-slot: rows rs*8 .. rs*8+7
    const float* meanp = tab + R_MEAN + fg * 8;
    const float* istdp = tab + R_ISTD + fg * 8;
    float istd[8], nmi[8];
#pragma unroll
    for (int j = 0; j < 8; j++) {
        float m = meanp[j];
        float is = istdp[j];
        istd[j] = is;
        nmi[j] = -m * is;
    }
    size_t idx = (size_t)rs * 8 * FEAT + fg * 8;
#pragma unroll
    for (int r = 0; r < 8; r++) {
        uint4 sv = *(const uint4*)(S + idx);
        float2 f0 = __half22float2(*(const __half2*)&sv.x);
        float2 f1 = __half22float2(*(const __half2*)&sv.y);
        float2 f2 = __half22float2(*(const __half2*)&sv.z);
        float2 f3 = __half22float2(*(const __half2*)&sv.w);
        float z0 = fmaf(f0.x, istd[0], nmi[0]);
        float z1 = fmaf(f0.y, istd[1], nmi[1]);
        float z2 = fmaf(f1.x, istd[2], nmi[2]);
        float z3 = fmaf(f1.y, istd[3], nmi[3]);
        float z4 = fmaf(f2.x, istd[4], nmi[4]);
        float z5 = fmaf(f2.y, istd[5], nmi[5]);
        float z6 = fmaf(f3.x, istd[6], nmi[6]);
        float z7 = fmaf(f3.y, istd[7], nmi[7]);
        float4* Zp = (float4*)(Z + idx);
        Zp[0] = make_float4(z0, z1, z2, z3);
        Zp[1] = make_float4(z4, z5, z6, z7);
        idx += FEAT;
    }
}

// Fallback pass2: recompute spline (when ws can't hold S).
__global__ __launch_bounds__(256, 6) void k_pass2_eval(const float* __restrict__ X,
                                                       const float* __restrict__ shiftp,
                                                       const float* __restrict__ scalep,
                                                       const float* __restrict__ tab,
                                                       float* __restrict__ Z) {
    __shared__ float4 sP0[16 * FTB];
    __shared__ float4 sP1[16 * FTB];
    int t = threadIdx.x;
    int rb = blockIdx.x, ft = blockIdx.y;
    const float4* P0g = (const float4*)(tab + R_P0);
    const float4* P1g = (const float4*)(tab + R_P1);
    for (int s = t; s < 16 * FTB; s += 256) {
        int bin = s >> 6, li = s & 63;
        sP0[s] = P0g[bin * 256 + ft * FTB + li];
        sP1[s] = P1g[bin * 256 + ft * FTB + li];
    }
    int l = t & 63, slot = t >> 6;
    int f = ft * FTB + l;
    float kn[15];
#pragma unroll
    for (int j = 0; j < 15; j++) kn[j] = tab[R_KN + j * 256 + f];
    float a = 1.0f / scalep[f];
    float nb = -shiftp[f] * a;
    float mean = tab[R_MEAN + f];
    float istd = tab[R_ISTD + f];
    __syncthreads();
    size_t base = ((size_t)rb * ROWS_PB + slot) * FEAT + f;
    const float* Xp = X + base;
    float* Zp = Z + base;
    for (int r = 0; r < ITERB; r += 4) {
        float x0 = Xp[0 * SLOTB * FEAT];
        float x1 = Xp[1 * SLOTB * FEAT];
        float x2 = Xp[2 * SLOTB * FEAT];
        float x3 = Xp[3 * SLOTB * FEAT];
        Xp += 4 * SLOTB * FEAT;
        float s0 = eval_rq(x0, a, nb, sP0, sP1, kn, l);
        float s1 = eval_rq(x1, a, nb, sP0, sP1, kn, l);
        float s2 = eval_rq(x2, a, nb, sP0, sP1, kn, l);
        float s3 = eval_rq(x3, a, nb, sP0, sP1, kn, l);
        Zp[0 * SLOTB * FEAT] = (s0 - mean) * istd;
        Zp[1 * SLOTB * FEAT] = (s1 - mean) * istd;
        Zp[2 * SLOTB * FEAT] = (s2 - mean) * istd;
        Zp[3 * SLOTB * FEAT] = (s3 - mean) * istd;
        Zp += 4 * SLOTB * FEAT;
    }
}

extern "C" void kernel_launch(void* const* d_in, const int* in_sizes, int n_in,
                              void* d_out, int out_size, void* d_ws, size_t ws_size,
                              hipStream_t stream) {
    const float* x     = (const float*)d_in[0];
    const float* uw    = (const float*)d_in[1];
    const float* uh    = (const float*)d_in[2];
    const float* ud    = (const float*)d_in[3];
    const float* shift = (const float*)d_in[4];
    const float* scale = (const float*)d_in[5];
    float* out = (float*)d_out;
    float* ws  = (float*)d_ws;

    size_t need = (S_FLOATS + (size_t)TAB_FLOATS) * sizeof(float);
    bool useS = ws_size >= need;
    float* tab = ws + (useS ? S_FLOATS : 0);
    unsigned short* S = (unsigned short*)ws;

    k_params<<<1, 256, 0, stream>>>(uw, uh, ud, tab);
    if (useS) {
        k_pass1<true><<<dim3(RBB, FT_TILES), 256, 0, stream>>>(x, shift, scale, tab, S);
        k_reduce<<<FEAT, 256, 0, stream>>>(tab);
        k_pass2_stream<<<2048, 256, 0, stream>>>(S, tab, out);
    } else {
        k_pass1<false><<<dim3(RBB, FT_TILES), 256, 0, stream>>>(x, shift, scale, tab, nullptr);
        k_reduce<<<FEAT, 256, 0, stream>>>(tab);
        k_pass2_eval<<<dim3(RBB, FT_TILES), 256, 0, stream>>>(x, shift, scale, tab, out);
    }
}

// Round 20
// 109.023 us; speedup vs baseline: 1.1037x; 1.1037x over previous
//
#include <hip/hip_runtime.h>
#include <hip/hip_fp16.h>
#include <math.h>

// MonotoneFeatureTransform: rational-quadratic spline per feature + batch standardize.
// B=131072, F=256, K=16. f32 in/out.
// FINAL (R20 = R18 champion, best measured 109.17us total):
//   pass1: FTB=32, SLOTB=8, batch-8, bin-major LDS [16][32] float4 (0 conflicts),
//     lb(256,6) (proven 6-blocks/CU residency, VGPR 40), alignbit+popcount scan
//     (2 instr/knot, no vcc serialization), f16 spill of s.
//   pass2: pure streaming standardize from f16 spill (HBM-floor bound).
// Plateau ledger: pass1 pinned at 78+-3us across 10 variants (occupancy 22-70%,
// ILP 4-8, prefetch/staging/issue-consume pipelines, 3 scan encodings, FTB 32/64).
// VALU-issue-bound at ~50% efficiency; the residual 2x to the ~40us issue floor
// is compiler-level (emitted-instruction count + issue stalls), not addressable
// from HIP source.
// BANNED (measured): nested-ternary select trees (R9 VGPR-collapse to 24),
// lb(256,8)/plain-lb (R4/R7/R8 collapse), data-dependent LDS reads feeding the
// table read (R11/R12 latency chains), FTB=64 at 34KB LDS (R19 occupancy 22%).

#define FEAT 256
#define KBINS 16
#define BATCH 131072
#define BOUNDF 5.0f
#define MIN_Df 1e-3f
#define MIN_BWf 1e-3f
#define MIN_BHf 1e-3f
#define EPSF 1e-8f

#define FTB 32                 // features per tile
#define FT_TILES 8
#define SLOTB 8                // row slots per block (256 thr / 32 feat)
#define RBB 256                // row-blocks
#define ROWS_PB (BATCH / RBB)  // 512 rows per block
#define ITERB (ROWS_PB / SLOTB) // 64 rows per thread

// Table region, float offsets relative to `tab`.
#define R_P0   0                    // [16][256] float4: cw0*binv, binv, h*delta, h*d0
#define R_P1   16384                // [16][256] float4: dsum, delta, ch0, pad
#define R_KN   32768                // [15][256] interior knots (cw[1..15])
#define R_MEAN 36608                // [256]
#define R_ISTD 36864                // [256]
#define R_PS   37120                // [2048][32] partial sums
#define R_PS2  (R_PS + 2048 * 32)   // [2048][32] partial sumsq
#define TAB_FLOATS (R_PS2 + 2048 * 32)
#define S_ELEMS ((size_t)BATCH * FEAT)
#define S_FLOATS (S_ELEMS / 2)

__global__ __launch_bounds__(256) void k_params(const float* __restrict__ uw,
                                                const float* __restrict__ uh,
                                                const float* __restrict__ ud,
                                                float* __restrict__ tab) {
    int f = threadIdx.x;
    float cw[17], ch[17], dv[17];
    {
        float u[KBINS];
#pragma unroll
        for (int j = 0; j < KBINS; j++) u[j] = uw[f * KBINS + j];
        float m = u[0];
#pragma unroll
        for (int j = 1; j < KBINS; j++) m = fmaxf(m, u[j]);
        float ssum = 0.f;
#pragma unroll
        for (int j = 0; j < KBINS; j++) { u[j] = expf(u[j] - m); ssum += u[j]; }
        float inv = 1.0f / ssum;
        float cum = 0.f;
        cw[0] = -BOUNDF;
#pragma unroll
        for (int j = 1; j < KBINS; j++) {
            float wj = MIN_BWf + (1.0f - MIN_BWf * (float)KBINS) * (u[j - 1] * inv);
            cum += wj;
            cw[j] = 2.0f * BOUNDF * cum - BOUNDF;
        }
        cw[KBINS] = BOUNDF;
    }
    {
        float u[KBINS];
#pragma unroll
        for (int j = 0; j < KBINS; j++) u[j] = uh[f * KBINS + j];
        float m = u[0];
#pragma unroll
        for (int j = 1; j < KBINS; j++) m = fmaxf(m, u[j]);
        float ssum = 0.f;
#pragma unroll
        for (int j = 0; j < KBINS; j++) { u[j] = expf(u[j] - m); ssum += u[j]; }
        float inv = 1.0f / ssum;
        float cum = 0.f;
        ch[0] = -BOUNDF;
#pragma unroll
        for (int j = 1; j < KBINS; j++) {
            float wj = MIN_BHf + (1.0f - MIN_BHf * (float)KBINS) * (u[j - 1] * inv);
            cum += wj;
            ch[j] = 2.0f * BOUNDF * cum - BOUNDF;
        }
        ch[KBINS] = BOUNDF;
    }
    {
        dv[0] = 1.0f;
        dv[KBINS] = 1.0f;
#pragma unroll
        for (int j = 1; j < KBINS; j++) {
            float v = ud[f * (KBINS - 1) + (j - 1)];
            float sp = fmaxf(v, 0.0f) + log1pf(expf(-fabsf(v))); // stable softplus
            dv[j] = MIN_Df + sp;
        }
    }
    // interior knots, feature-minor for coalesced reads
#pragma unroll
    for (int j = 0; j < 15; j++) tab[R_KN + j * 256 + f] = cw[j + 1];
    // packed per-bin params, BIN-MAJOR: [bin][feature]
    float4* P0g = (float4*)(tab + R_P0);
    float4* P1g = (float4*)(tab + R_P1);
#pragma unroll
    for (int i = 0; i < KBINS; i++) {
        float w = cw[i + 1] - cw[i];
        float binv = 1.0f / w;
        float hb = ch[i + 1] - ch[i];
        float delta = hb * binv;
        float4 p0, p1;
        p0.x = cw[i] * binv;
        p0.y = binv;
        p0.z = hb * delta;
        p0.w = hb * dv[i];
        p1.x = dv[i] + dv[i + 1] - 2.0f * delta;
        p1.y = delta;
        p1.z = ch[i];
        p1.w = 0.0f;
        P0g[i * 256 + f] = p0;
        P1g[i * 256 + f] = p1;
    }
}

// alignbit+popcount scan + rational-quadratic eval (bin-major LDS [16][32]).
// w = (w<<1)|signbit(kn[j]-xn) via v_alignbit_b32; idx = popcount(w) counts
// kn[j] < xn. Differs from (xn>=kn[j]) only at exact ties, where the spline
// is continuous -> identical result.
__device__ __forceinline__ float eval_rq(float xv, float a, float nb,
                                         const float4* __restrict__ sP0,
                                         const float4* __restrict__ sP1,
                                         const float kn[15], int l) {
    float xn = fmaf(xv, a, nb);
    unsigned int w = 0u;
#pragma unroll
    for (int j = 0; j < 15; j++) {
        float d = kn[j] - xn;                                     // independent subs
        w = __builtin_amdgcn_alignbit(w, __float_as_uint(d), 31); // w=(w<<1)|sign(d)
    }
    int idx = __builtin_popcount(w);                              // v_bcnt_u32_b32
    int o = (idx << 5) | l;
    float4 p0 = sP0[o];
    float4 p1 = sP1[o];
    float th = fmaf(xn, p0.y, -p0.x);
    float th2 = th * th;
    float t1m = th - th2;
    float numer = fmaf(p0.z, th2, p0.w * t1m);
    float denom = fmaf(p1.x, t1m, p1.y);
    float s = fmaf(numer, __builtin_amdgcn_rcpf(denom), p1.z);
    return (fabsf(xn) < BOUNDF) ? s : xn;
}

template <bool STORE_S>
__global__ __launch_bounds__(256, 6) void k_pass1(const float* __restrict__ X,
                                                  const float* __restrict__ shiftp,
                                                  const float* __restrict__ scalep,
                                                  float* __restrict__ tab,
                                                  unsigned short* __restrict__ S) {
    __shared__ float4 sP0[16 * FTB];
    __shared__ float4 sP1[16 * FTB];
    __shared__ float red[2][SLOTB][FTB];
    int t = threadIdx.x;
    int rb = blockIdx.x, ft = blockIdx.y;
    const float4* P0g = (const float4*)(tab + R_P0);
    const float4* P1g = (const float4*)(tab + R_P1);
    for (int s = t; s < 16 * FTB; s += 256) {
        int bin = s >> 5, li = s & 31;
        sP0[s] = P0g[bin * 256 + ft * FTB + li];
        sP1[s] = P1g[bin * 256 + ft * FTB + li];
    }
    int l = t & 31, slot = t >> 5;
    int f = ft * FTB + l;
    float kn[15];
#pragma unroll
    for (int j = 0; j < 15; j++) kn[j] = tab[R_KN + j * 256 + f];
    float a = 1.0f / scalep[f];
    float nb = -shiftp[f] * a;
    __syncthreads();
    size_t base = ((size_t)rb * ROWS_PB + slot) * FEAT + f;
    const float* Xp = X + base;
    unsigned short* Sp = STORE_S ? (S + base) : nullptr;
    float sum = 0.f, sumsq = 0.f;
    for (int r = 0; r < ITERB; r += 8) {
        float xv[8];
#pragma unroll
        for (int i = 0; i < 8; i++) xv[i] = Xp[i * SLOTB * FEAT];
        Xp += 8 * SLOTB * FEAT;
        float sv[8];
#pragma unroll
        for (int i = 0; i < 8; i++) sv[i] = eval_rq(xv[i], a, nb, sP0, sP1, kn, l);
        if (STORE_S) {
#pragma unroll
            for (int i = 0; i < 8; i++) Sp[i * SLOTB * FEAT] = __half_as_ushort(__float2half(sv[i]));
            Sp += 8 * SLOTB * FEAT;
        }
#pragma unroll
        for (int i = 0; i < 8; i++) { sum += sv[i]; sumsq = fmaf(sv[i], sv[i], sumsq); }
    }
    red[0][slot][l] = sum;
    red[1][slot][l] = sumsq;
    __syncthreads();
    if (t < FTB) {
        float v = 0.f;
#pragma unroll
        for (int s2i = 0; s2i < SLOTB; s2i++) v += red[0][s2i][t];
        tab[R_PS + (ft * RBB + rb) * FTB + t] = v;
    } else if (t < 2 * FTB) {
        int u = t - FTB;
        float v = 0.f;
#pragma unroll
        for (int s2i = 0; s2i < SLOTB; s2i++) v += red[1][s2i][u];
        tab[R_PS2 + (ft * RBB + rb) * FTB + u] = v;
    }
}

__global__ __launch_bounds__(256) void k_reduce(float* __restrict__ tab) {
    int f = blockIdx.x;
    int ft = f >> 5, l = f & 31;
    int t = threadIdx.x;
    __shared__ float r1[256], r2[256];
    r1[t] = tab[R_PS + (ft * RBB + t) * FTB + l];
    r2[t] = tab[R_PS2 + (ft * RBB + t) * FTB + l];
    __syncthreads();
    for (int off = 128; off > 0; off >>= 1) {
        if (t < off) { r1[t] += r1[t + off]; r2[t] += r2[t + off]; }
        __syncthreads();
    }
    if (t == 0) {
        float mean = r1[0] * (1.0f / (float)BATCH);
        float var = r2[0] * (1.0f / (float)BATCH) - mean * mean;
        var = fmaxf(var, 0.0f);
        tab[R_MEAN + f] = mean;
        tab[R_ISTD + f] = 1.0f / sqrtf(var + EPSF);
    }
}

// Streaming standardize: z = s*istd - mean*istd, s from f16 buffer.
__global__ __launch_bounds__(256, 8) void k_pass2_stream(const unsigned short* __restrict__ S,
                                                         const float* __restrict__ tab,
                                                         float* __restrict__ Z) {
    int gid = blockIdx.x * 256 + threadIdx.x;   // 524288 threads
    int fg = gid & 31;                          // feature-group: features fg*8 .. fg*8+7
    int rs = gid >> 5;                          // row-slot: rows rs*8 .. rs*8+7
    const float* meanp = tab + R_MEAN + fg * 8;
    const float* istdp = tab + R_ISTD + fg * 8;
    float istd[8], nmi[8];
#pragma unroll
    for (int j = 0; j < 8; j++) {
        float m = meanp[j];
        float is = istdp[j];
        istd[j] = is;
        nmi[j] = -m * is;
    }
    size_t idx = (size_t)rs * 8 * FEAT + fg * 8;
#pragma unroll
    for (int r = 0; r < 8; r++) {
        uint4 sv = *(const uint4*)(S + idx);
        float2 f0 = __half22float2(*(const __half2*)&sv.x);
        float2 f1 = __half22float2(*(const __half2*)&sv.y);
        float2 f2 = __half22float2(*(const __half2*)&sv.z);
        float2 f3 = __half22float2(*(const __half2*)&sv.w);
        float z0 = fmaf(f0.x, istd[0], nmi[0]);
        float z1 = fmaf(f0.y, istd[1], nmi[1]);
        float z2 = fmaf(f1.x, istd[2], nmi[2]);
        float z3 = fmaf(f1.y, istd[3], nmi[3]);
        float z4 = fmaf(f2.x, istd[4], nmi[4]);
        float z5 = fmaf(f2.y, istd[5], nmi[5]);
        float z6 = fmaf(f3.x, istd[6], nmi[6]);
        float z7 = fmaf(f3.y, istd[7], nmi[7]);
        float4* Zp = (float4*)(Z + idx);
        Zp[0] = make_float4(z0, z1, z2, z3);
        Zp[1] = make_float4(z4, z5, z6, z7);
        idx += FEAT;
    }
}

// Fallback pass2: recompute spline (when ws can't hold S).
__global__ __launch_bounds__(256, 6) void k_pass2_eval(const float* __restrict__ X,
                                                       const float* __restrict__ shiftp,
                                                       const float* __restrict__ scalep,
                                                       const float* __restrict__ tab,
                                                       float* __restrict__ Z) {
    __shared__ float4 sP0[16 * FTB];
    __shared__ float4 sP1[16 * FTB];
    int t = threadIdx.x;
    int rb = blockIdx.x, ft = blockIdx.y;
    const float4* P0g = (const float4*)(tab + R_P0);
    const float4* P1g = (const float4*)(tab + R_P1);
    for (int s = t; s < 16 * FTB; s += 256) {
        int bin = s >> 5, li = s & 31;
        sP0[s] = P0g[bin * 256 + ft * FTB + li];
        sP1[s] = P1g[bin * 256 + ft * FTB + li];
    }
    int l = t & 31, slot = t >> 5;
    int f = ft * FTB + l;
    float kn[15];
#pragma unroll
    for (int j = 0; j < 15; j++) kn[j] = tab[R_KN + j * 256 + f];
    float a = 1.0f / scalep[f];
    float nb = -shiftp[f] * a;
    float mean = tab[R_MEAN + f];
    float istd = tab[R_ISTD + f];
    __syncthreads();
    size_t base = ((size_t)rb * ROWS_PB + slot) * FEAT + f;
    const float* Xp = X + base;
    float* Zp = Z + base;
    for (int r = 0; r < ITERB; r += 4) {
        float x0 = Xp[0 * SLOTB * FEAT];
        float x1 = Xp[1 * SLOTB * FEAT];
        float x2 = Xp[2 * SLOTB * FEAT];
        float x3 = Xp[3 * SLOTB * FEAT];
        Xp += 4 * SLOTB * FEAT;
        float s0 = eval_rq(x0, a, nb, sP0, sP1, kn, l);
        float s1 = eval_rq(x1, a, nb, sP0, sP1, kn, l);
        float s2 = eval_rq(x2, a, nb, sP0, sP1, kn, l);
        float s3 = eval_rq(x3, a, nb, sP0, sP1, kn, l);
        Zp[0 * SLOTB * FEAT] = (s0 - mean) * istd;
        Zp[1 * SLOTB * FEAT] = (s1 - mean) * istd;
        Zp[2 * SLOTB * FEAT] = (s2 - mean) * istd;
        Zp[3 * SLOTB * FEAT] = (s3 - mean) * istd;
        Zp += 4 * SLOTB * FEAT;
    }
}

extern "C" void kernel_launch(void* const* d_in, const int* in_sizes, int n_in,
                              void* d_out, int out_size, void* d_ws, size_t ws_size,
                              hipStream_t stream) {
    const float* x     = (const float*)d_in[0];
    const float* uw    = (const float*)d_in[1];
    const float* uh    = (const float*)d_in[2];
    const float* ud    = (const float*)d_in[3];
    const float* shift = (const float*)d_in[4];
    const float* scale = (const float*)d_in[5];
    float* out = (float*)d_out;
    float* ws  = (float*)d_ws;

    size_t need = (S_FLOATS + (size_t)TAB_FLOATS) * sizeof(float);
    bool useS = ws_size >= need;
    float* tab = ws + (useS ? S_FLOATS : 0);
    unsigned short* S = (unsigned short*)ws;

    k_params<<<1, 256, 0, stream>>>(uw, uh, ud, tab);
    if (useS) {
        k_pass1<true><<<dim3(RBB, FT_TILES), 256, 0, stream>>>(x, shift, scale, tab, S);
        k_reduce<<<FEAT, 256, 0, stream>>>(tab);
        k_pass2_stream<<<2048, 256, 0, stream>>>(S, tab, out);
    } else {
        k_pass1<false><<<dim3(RBB, FT_TILES), 256, 0, stream>>>(x, shift, scale, tab, nullptr);
        k_reduce<<<FEAT, 256, 0, stream>>>(tab);
        k_pass2_eval<<<dim3(RBB, FT_TILES), 256, 0, stream>>>(x, shift, scale, tab, out);
    }
}